// Round 2
// baseline (661.732 us; speedup 1.0000x reference)
//
#include <hip/hip_runtime.h>
#include <hip/hip_bf16.h>
#include <stdint.h>

typedef __attribute__((ext_vector_type(8))) short  short8;
typedef __attribute__((ext_vector_type(4))) float  float4_t;
typedef __attribute__((ext_vector_type(4))) int    int4_t;

constexpr int BB = 4, CIN = 64, COUT = 64, HH = 384, WW = 384;
constexpr int HWc  = HH * WW;        // 147456
constexpr int NPIX = BB * HWc;       // 589824
// main-kernel tiling
constexpr int TR = 8, TC = 32;           // pixel tile per WG
constexpr int SR = TR + 2, SC = TC + 2;  // staged rows/cols (10, 34)
constexpr int NG = 10;                   // 16B-aligned 4-col groups per row (cols x0-4 .. x0+35)
constexpr int NTASK = SR * NG * 8;       // staging tasks: row x group x 8-cin-group = 800
constexpr int NXTILE = WW / TC;          // 12
constexpr int NYTILE = HH / TR;          // 48
constexpr int NBLK  = NXTILE * NYTILE * BB;   // 2304
constexpr int XCD_CHUNK = NBLK / 8;           // 288 (2304 % 8 == 0 -> bijective)

__device__ __forceinline__ unsigned short f2bf(float f) {
    unsigned u = __builtin_bit_cast(unsigned, f);
    unsigned r = u + 0x7FFFu + ((u >> 16) & 1u);   // RNE
    return (unsigned short)(r >> 16);
}

// one instr: packs bf16(lo) | bf16(hi)<<16, RNE (same result as f2bf pair)
__device__ __forceinline__ unsigned cvtpk(float lo, float hi) {
    unsigned r;
    asm("v_cvt_pk_bf16_f32 %0, %1, %2" : "=v"(r) : "v"(lo), "v"(hi));
    return r;
}

// ---------------- merged prep: route flags + weight pack ----------------
// Wp[chunk 0..17][tile 0..4][lane 0..63][8] bf16 ; chunk = tap*2 + h, k = 32h + quad*8 + j
// Ap2[tile 0..3][lane][8] bf16 for the 1x1 (k = (c>>2)*8 + (c&3), j>=4 zero)
__global__ void k_prep(const int* __restrict__ mi, const int* __restrict__ ii,
                       unsigned char* __restrict__ flags, int half,
                       const float* __restrict__ hw_, const float* __restrict__ l1w,
                       const float* __restrict__ l2w,
                       unsigned short* __restrict__ Wp, unsigned short* __restrict__ Ap2) {
    int i = blockIdx.x * 256 + threadIdx.x;
    if (i < half) { flags[mi[i]] = 1; flags[ii[i]] = 0; }
    if (i < 18 * 5 * 64) {
        int lane = i & 63, tile = (i >> 6) % 5, chunk = i / 320;
        int tap = chunk >> 1, h = chunk & 1, ky = tap / 3, kx = tap % 3;
        int m = lane & 15, quad = lane >> 4;
        for (int j = 0; j < 8; j++) {
            int cin = h * 32 + quad * 8 + j;
            float wv;
            if (tile < 4) { int co = tile * 16 + m; wv = hw_[((co * 64 + cin) * 3 + ky) * 3 + kx]; }
            else          { wv = l1w[((m * 64 + cin) * 3 + ky) * 3 + kx]; }
            Wp[(size_t)i * 8 + j] = f2bf(wv);
        }
    }
    if (i < 4 * 64) {
        int lane = i & 63, tile = i >> 6;
        int m = lane & 15, quad = lane >> 4;
        for (int j = 0; j < 8; j++) {
            unsigned short v = 0;
            if (j < 4) { int c = quad * 4 + j; v = f2bf(l2w[(tile * 16 + m) * 16 + c]); }
            Ap2[(size_t)i * 8 + j] = v;
        }
    }
}

// ---------------- main fused MFMA kernel (reads NCHW fp32 directly) ----------------
// WG = 512 thr = 8 waves on the SAME 8x32 tile; wave w owns row w (2 col-half frags).
// LDS 43.5 KB -> still 3 blocks/CU resident, but now 24 waves/CU (vs 12) for latency hiding.
// 1D grid, XCD-bijective swizzle. Staging task = (row, aligned 4-col group, 8-cin group):
// 8x ALIGNED global_load_dwordx4, v_cvt_pk_bf16_f32 repack, ds_write_b128 swizzled.
__global__ __launch_bounds__(512, 6) void k_main(
    const float* __restrict__ x,
    const unsigned short* __restrict__ Wp,
    const unsigned short* __restrict__ Ap2,
    const unsigned char* __restrict__ flags,
    float* __restrict__ out)
{
    __shared__ __align__(16) unsigned short X[SR * SC * 64];  // 43520 B -> 3 blocks/CU

    const int tid = threadIdx.x;

    // XCD-aware bijective swizzle (2304 % 8 == 0)
    const int lin = blockIdx.x;
    const int des = (lin & 7) * XCD_CHUNK + (lin >> 3);
    const int xt  = des % NXTILE;
    const int rst = des / NXTILE;
    const int yt  = rst % NYTILE;
    const int b   = rst / NYTILE;
    const int x0  = xt * TC;
    const int y0  = yt * TR;

    const int lane = tid & 63;

    // issue first weight-chunk loads early (independent of staging)
    const int4_t* wp4 = (const int4_t*)Wp;
    short8 a_cur[5], a_nxt[5];
#pragma unroll
    for (int t = 0; t < 5; t++)
        a_cur[t] = __builtin_bit_cast(short8, wp4[t * 64 + lane]);

    // ---- stage tile: global NCHW fp32 -> LDS bf16 fragment layout ----
    const float* xb = x + (size_t)b * CIN * HWc;
#pragma unroll 1
    for (int t = tid; t < NTASK; t += 512) {
        int g   = t % NG;                // aligned 4-col group: cols 4g-4 .. 4g-1 rel. to x0
        int q   = (t / NG) & 7;          // 8-cin group
        int row = t / (NG * 8);
        int gy  = y0 + row - 1;
        int gx0 = x0 - 4 + g * 4;        // multiple of 4 -> 16B-aligned address
        bool yok  = (unsigned)gy < (unsigned)HH;
        bool fast = yok && (gx0 >= 0) && (gx0 <= WW - 4);
        const float* xp = xb + (size_t)(q * 8) * HWc + gy * WW + gx0;
        float4_t v[8];
        if (fast) {
#pragma unroll
            for (int c = 0; c < 8; c++)
                v[c] = *(const float4_t*)(xp + (size_t)c * HWc);
        } else {
#pragma unroll
            for (int c = 0; c < 8; c++)
#pragma unroll
                for (int e = 0; e < 4; e++) {
                    bool ok = yok && ((unsigned)(gx0 + e) < (unsigned)WW);
                    v[c][e] = ok ? xp[(size_t)c * HWc + e] : 0.f;
                }
        }
#pragma unroll
        for (int e = 0; e < 4; e++) {
            int col = g * 4 + e - 3;     // LDS col = gx - (x0-1); each col covered exactly once
            if ((unsigned)col < (unsigned)SC) {
                int4_t pk;
#pragma unroll
                for (int jj = 0; jj < 4; jj++)
                    pk[jj] = (int)cvtpk(v[2 * jj][e], v[2 * jj + 1][e]);
                int blk = q ^ (col & 7);
                *(int4_t*)&X[(row * SC + col) * 64 + blk * 8] = pk;
            }
        }
    }
    __syncthreads();

    const int w    = tid >> 6;       // wave 0..7 owns pixel row w
    const int n16  = lane & 15;
    const int quad = lane >> 4;

    float4_t acc[5][2];
#pragma unroll
    for (int t = 0; t < 5; t++)
#pragma unroll
        for (int f = 0; f < 2; f++) acc[t][f] = (float4_t)0.0f;

#pragma unroll 1
    for (int chunk = 0; chunk < 18; chunk++) {
        if (chunk < 17) {
#pragma unroll
            for (int t = 0; t < 5; t++)
                a_nxt[t] = __builtin_bit_cast(short8, wp4[((chunk + 1) * 5 + t) * 64 + lane]);
        }
        const int tap = chunk >> 1, h = chunk & 1;
        const int ky = tap / 3, kx = tap % 3;
        short8 bf[2];
#pragma unroll
        for (int f = 0; f < 2; f++) {
            int xh  = f * 16 + n16 + kx;
            int blk = (h * 4 + quad) ^ (xh & 7);
            bf[f] = __builtin_bit_cast(short8,
                    *(const int4_t*)&X[((w + ky) * SC + xh) * 64 + blk * 8]);
        }
#pragma unroll
        for (int f = 0; f < 2; f++)
#pragma unroll
            for (int t = 0; t < 5; t++)
                acc[t][f] = __builtin_amdgcn_mfma_f32_16x16x32_bf16(a_cur[t], bf[f], acc[t][f], 0, 0, 0);
#pragma unroll
        for (int t = 0; t < 5; t++) a_cur[t] = a_nxt[t];
    }

    // ---- epilogue: 1x1 low path via MFMA, routed select, nontemporal store ----
    short8 a2[4];
    const int4_t* ap4 = (const int4_t*)Ap2;
#pragma unroll
    for (int t = 0; t < 4; t++)
        a2[t] = __builtin_bit_cast(short8, ap4[t * 64 + lane]);

#pragma unroll
    for (int f = 0; f < 2; f++) {
        float4_t m4 = acc[4][f];
        int4_t bi;
        bi[0] = (int)cvtpk(m4[0], m4[1]);
        bi[1] = (int)cvtpk(m4[2], m4[3]);
        bi[2] = 0;
        bi[3] = 0;
        short8 bfrag = __builtin_bit_cast(short8, bi);

        int gy = y0 + w, gx = x0 + f * 16 + n16;
        bool hiF = flags[b * HWc + gy * WW + gx] != 0;
        float* ob = out + (size_t)b * COUT * HWc + gy * WW + gx;
#pragma unroll
        for (int t = 0; t < 4; t++) {
            float4_t low = __builtin_amdgcn_mfma_f32_16x16x32_bf16(a2[t], bfrag, (float4_t)0.0f, 0, 0, 0);
            float4_t hi = acc[t][f];
#pragma unroll
            for (int i = 0; i < 4; i++) {
                int co = t * 16 + quad * 4 + i;
                __builtin_nontemporal_store(hiF ? hi[i] : low[i], ob + (size_t)co * HWc);
            }
        }
    }
}

extern "C" void kernel_launch(void* const* d_in, const int* in_sizes, int n_in,
                              void* d_out, int out_size, void* d_ws, size_t ws_size,
                              hipStream_t stream) {
    const float* x   = (const float*)d_in[0];
    const float* hw_ = (const float*)d_in[1];
    const float* l1w = (const float*)d_in[2];
    const float* l2w = (const float*)d_in[3];
    const int*   mi  = (const int*)d_in[4];
    const int*   ii  = (const int*)d_in[5];
    float*       out = (float*)d_out;

    // ws carve
    unsigned char*  flags = (unsigned char*)d_ws;
    size_t off = (NPIX + 15) & ~(size_t)15;
    unsigned short* Wp    = (unsigned short*)((char*)d_ws + off); off += 18 * 5 * 64 * 8 * 2;
    unsigned short* Ap2   = (unsigned short*)((char*)d_ws + off);

    const int half = NPIX / 2;
    k_prep<<<(half + 255) / 256, 256, 0, stream>>>(mi, ii, flags, half, hw_, l1w, l2w, Wp, Ap2);
    k_main<<<NBLK, 512, 0, stream>>>(x, Wp, Ap2, flags, out);
}

// Round 3
// 655.723 us; speedup vs baseline: 1.0092x; 1.0092x over previous
//
#include <hip/hip_runtime.h>
#include <hip/hip_bf16.h>
#include <stdint.h>

typedef __attribute__((ext_vector_type(8))) short  short8;
typedef __attribute__((ext_vector_type(4))) float  float4_t;
typedef __attribute__((ext_vector_type(4))) int    int4_t;

constexpr int BB = 4, CIN = 64, COUT = 64, HH = 384, WW = 384;
constexpr int HWc  = HH * WW;        // 147456
constexpr int NPIX = BB * HWc;       // 589824
// main-kernel tiling
constexpr int TR = 8, TC = 32;           // pixel tile per WG
constexpr int SR = TR + 2, SC = TC + 2;  // staged rows/cols (10, 34)
constexpr int NG = 10;                   // 16B-aligned 4-col groups per row (cols x0-4 .. x0+35)
constexpr int NTASK = SR * NG * 8;       // staging tasks: row x group x 8-cin-group = 800
constexpr int NXTILE = WW / TC;          // 12
constexpr int NYTILE = HH / TR;          // 48
constexpr int NBLK  = NXTILE * NYTILE * BB;   // 2304
constexpr int XCD_CHUNK = NBLK / 8;           // 288 (2304 % 8 == 0 -> bijective)

__device__ __forceinline__ unsigned short f2bf(float f) {
    unsigned u = __builtin_bit_cast(unsigned, f);
    unsigned r = u + 0x7FFFu + ((u >> 16) & 1u);   // RNE
    return (unsigned short)(r >> 16);
}

// one instr: packs bf16(lo) | bf16(hi)<<16, RNE (same result as f2bf pair)
__device__ __forceinline__ unsigned cvtpk(float lo, float hi) {
    unsigned r;
    asm("v_cvt_pk_bf16_f32 %0, %1, %2" : "=v"(r) : "v"(lo), "v"(hi));
    return r;
}

// ---------------- merged prep: route flags + weight pack ----------------
// Wp[chunk 0..17][tile 0..4][lane 0..63][8] bf16 ; chunk = tap*2 + h, k = 32h + quad*8 + j
// Ap2[tile 0..3][lane][8] bf16 for the 1x1 (k = (c>>2)*8 + (c&3), j>=4 zero)
__global__ void k_prep(const int* __restrict__ mi, const int* __restrict__ ii,
                       unsigned char* __restrict__ flags, int half,
                       const float* __restrict__ hw_, const float* __restrict__ l1w,
                       const float* __restrict__ l2w,
                       unsigned short* __restrict__ Wp, unsigned short* __restrict__ Ap2) {
    int i = blockIdx.x * 256 + threadIdx.x;
    if (i < half) { flags[mi[i]] = 1; flags[ii[i]] = 0; }
    if (i < 18 * 5 * 64) {
        int lane = i & 63, tile = (i >> 6) % 5, chunk = i / 320;
        int tap = chunk >> 1, h = chunk & 1, ky = tap / 3, kx = tap % 3;
        int m = lane & 15, quad = lane >> 4;
        for (int j = 0; j < 8; j++) {
            int cin = h * 32 + quad * 8 + j;
            float wv;
            if (tile < 4) { int co = tile * 16 + m; wv = hw_[((co * 64 + cin) * 3 + ky) * 3 + kx]; }
            else          { wv = l1w[((m * 64 + cin) * 3 + ky) * 3 + kx]; }
            Wp[(size_t)i * 8 + j] = f2bf(wv);
        }
    }
    if (i < 4 * 64) {
        int lane = i & 63, tile = i >> 6;
        int m = lane & 15, quad = lane >> 4;
        for (int j = 0; j < 8; j++) {
            unsigned short v = 0;
            if (j < 4) { int c = quad * 4 + j; v = f2bf(l2w[(tile * 16 + m) * 16 + c]); }
            Ap2[(size_t)i * 8 + j] = v;
        }
    }
}

// ---------------- main fused MFMA kernel (reads NCHW fp32 directly) ----------------
// WG = 512 thr = 8 waves on the SAME 8x32 tile; wave w owns row w (2 col-half frags).
// LDS 43.5 KB -> 3 blocks/CU resident, 24 waves/CU for latency hiding.
// 1D grid, XCD-bijective swizzle. Staging task = (row, aligned 4-col group, 8-cin group):
// 8x ALIGNED global_load_dwordx4, v_cvt_pk_bf16_f32 repack, ds_write_b128 swizzled.
// NOTE: plain stores only — nontemporal stores caused 5.3x write amplification
// (64B segments bypass L2 merge into 256B HBM atoms). Measured round 2.
__global__ __launch_bounds__(512, 6) void k_main(
    const float* __restrict__ x,
    const unsigned short* __restrict__ Wp,
    const unsigned short* __restrict__ Ap2,
    const unsigned char* __restrict__ flags,
    float* __restrict__ out)
{
    __shared__ __align__(16) unsigned short X[SR * SC * 64];  // 43520 B -> 3 blocks/CU

    const int tid = threadIdx.x;

    // XCD-aware bijective swizzle (2304 % 8 == 0)
    const int lin = blockIdx.x;
    const int des = (lin & 7) * XCD_CHUNK + (lin >> 3);
    const int xt  = des % NXTILE;
    const int rst = des / NXTILE;
    const int yt  = rst % NYTILE;
    const int b   = rst / NYTILE;
    const int x0  = xt * TC;
    const int y0  = yt * TR;

    const int lane = tid & 63;

    // issue first weight-chunk loads early (independent of staging)
    const int4_t* wp4 = (const int4_t*)Wp;
    short8 a_cur[5], a_nxt[5];
#pragma unroll
    for (int t = 0; t < 5; t++)
        a_cur[t] = __builtin_bit_cast(short8, wp4[t * 64 + lane]);

    // ---- stage tile: global NCHW fp32 -> LDS bf16 fragment layout ----
    const float* xb = x + (size_t)b * CIN * HWc;
#pragma unroll 1
    for (int t = tid; t < NTASK; t += 512) {
        int g   = t % NG;                // aligned 4-col group: cols 4g-4 .. 4g-1 rel. to x0
        int q   = (t / NG) & 7;          // 8-cin group
        int row = t / (NG * 8);
        int gy  = y0 + row - 1;
        int gx0 = x0 - 4 + g * 4;        // multiple of 4 -> 16B-aligned address
        bool yok  = (unsigned)gy < (unsigned)HH;
        bool fast = yok && (gx0 >= 0) && (gx0 <= WW - 4);
        const float* xp = xb + (size_t)(q * 8) * HWc + gy * WW + gx0;
        float4_t v[8];
        if (fast) {
#pragma unroll
            for (int c = 0; c < 8; c++)
                v[c] = *(const float4_t*)(xp + (size_t)c * HWc);
        } else {
#pragma unroll
            for (int c = 0; c < 8; c++)
#pragma unroll
                for (int e = 0; e < 4; e++) {
                    bool ok = yok && ((unsigned)(gx0 + e) < (unsigned)WW);
                    v[c][e] = ok ? xp[(size_t)c * HWc + e] : 0.f;
                }
        }
#pragma unroll
        for (int e = 0; e < 4; e++) {
            int col = g * 4 + e - 3;     // LDS col = gx - (x0-1); each col covered exactly once
            if ((unsigned)col < (unsigned)SC) {
                int4_t pk;
#pragma unroll
                for (int jj = 0; jj < 4; jj++)
                    pk[jj] = (int)cvtpk(v[2 * jj][e], v[2 * jj + 1][e]);
                int blk = q ^ (col & 7);
                *(int4_t*)&X[(row * SC + col) * 64 + blk * 8] = pk;
            }
        }
    }
    __syncthreads();

    const int w    = tid >> 6;       // wave 0..7 owns pixel row w
    const int n16  = lane & 15;
    const int quad = lane >> 4;

    float4_t acc[5][2];
#pragma unroll
    for (int t = 0; t < 5; t++)
#pragma unroll
        for (int f = 0; f < 2; f++) acc[t][f] = (float4_t)0.0f;

#pragma unroll 1
    for (int chunk = 0; chunk < 18; chunk++) {
        if (chunk < 17) {
#pragma unroll
            for (int t = 0; t < 5; t++)
                a_nxt[t] = __builtin_bit_cast(short8, wp4[((chunk + 1) * 5 + t) * 64 + lane]);
        }
        const int tap = chunk >> 1, h = chunk & 1;
        const int ky = tap / 3, kx = tap % 3;
        short8 bf[2];
#pragma unroll
        for (int f = 0; f < 2; f++) {
            int xh  = f * 16 + n16 + kx;
            int blk = (h * 4 + quad) ^ (xh & 7);
            bf[f] = __builtin_bit_cast(short8,
                    *(const int4_t*)&X[((w + ky) * SC + xh) * 64 + blk * 8]);
        }
#pragma unroll
        for (int f = 0; f < 2; f++)
#pragma unroll
            for (int t = 0; t < 5; t++)
                acc[t][f] = __builtin_amdgcn_mfma_f32_16x16x32_bf16(a_cur[t], bf[f], acc[t][f], 0, 0, 0);
#pragma unroll
        for (int t = 0; t < 5; t++) a_cur[t] = a_nxt[t];
    }

    // ---- epilogue: 1x1 low path via MFMA, routed select, plain store ----
    short8 a2[4];
    const int4_t* ap4 = (const int4_t*)Ap2;
#pragma unroll
    for (int t = 0; t < 4; t++)
        a2[t] = __builtin_bit_cast(short8, ap4[t * 64 + lane]);

#pragma unroll
    for (int f = 0; f < 2; f++) {
        float4_t m4 = acc[4][f];
        int4_t bi;
        bi[0] = (int)cvtpk(m4[0], m4[1]);
        bi[1] = (int)cvtpk(m4[2], m4[3]);
        bi[2] = 0;
        bi[3] = 0;
        short8 bfrag = __builtin_bit_cast(short8, bi);

        int gy = y0 + w, gx = x0 + f * 16 + n16;
        bool hiF = flags[b * HWc + gy * WW + gx] != 0;
        float* ob = out + (size_t)b * COUT * HWc + gy * WW + gx;
#pragma unroll
        for (int t = 0; t < 4; t++) {
            float4_t low = __builtin_amdgcn_mfma_f32_16x16x32_bf16(a2[t], bfrag, (float4_t)0.0f, 0, 0, 0);
            float4_t hi = acc[t][f];
#pragma unroll
            for (int i = 0; i < 4; i++) {
                int co = t * 16 + quad * 4 + i;
                ob[(size_t)co * HWc] = hiF ? hi[i] : low[i];
            }
        }
    }
}

extern "C" void kernel_launch(void* const* d_in, const int* in_sizes, int n_in,
                              void* d_out, int out_size, void* d_ws, size_t ws_size,
                              hipStream_t stream) {
    const float* x   = (const float*)d_in[0];
    const float* hw_ = (const float*)d_in[1];
    const float* l1w = (const float*)d_in[2];
    const float* l2w = (const float*)d_in[3];
    const int*   mi  = (const int*)d_in[4];
    const int*   ii  = (const int*)d_in[5];
    float*       out = (float*)d_out;

    // ws carve
    unsigned char*  flags = (unsigned char*)d_ws;
    size_t off = (NPIX + 15) & ~(size_t)15;
    unsigned short* Wp    = (unsigned short*)((char*)d_ws + off); off += 18 * 5 * 64 * 8 * 2;
    unsigned short* Ap2   = (unsigned short*)((char*)d_ws + off);

    const int half = NPIX / 2;
    k_prep<<<(half + 255) / 256, 256, 0, stream>>>(mi, ii, flags, half, hw_, l1w, l2w, Wp, Ap2);
    k_main<<<NBLK, 512, 0, stream>>>(x, Wp, Ap2, flags, out);
}

// Round 4
// 331.477 us; speedup vs baseline: 1.9963x; 1.9782x over previous
//
#include <hip/hip_runtime.h>
#include <hip/hip_bf16.h>
#include <stdint.h>

typedef __attribute__((ext_vector_type(8))) short  short8;
typedef __attribute__((ext_vector_type(4))) float  float4_t;
typedef __attribute__((ext_vector_type(4))) int    int4_t;

constexpr int BB = 4, CIN = 64, COUT = 64, HH = 384, WW = 384;
constexpr int HWc  = HH * WW;        // 147456
constexpr int NPIX = BB * HWc;       // 589824
// main-kernel tiling
constexpr int TR = 8, TC = 32;           // pixel tile per WG
constexpr int SR = TR + 2, SC = TC + 2;  // staged rows/cols (10, 34)
constexpr int NG = 10;                   // 16B-aligned 4-col groups per row (cols x0-4 .. x0+35)
constexpr int NTASK = SR * NG * 8;       // staging tasks: row x group x 8-cin-group = 800
constexpr int NXTILE = WW / TC;          // 12
constexpr int NYTILE = HH / TR;          // 48
constexpr int NBLK  = NXTILE * NYTILE * BB;   // 2304
constexpr int XCD_CHUNK = NBLK / 8;           // 288 (2304 % 8 == 0 -> bijective)

__device__ __forceinline__ unsigned short f2bf(float f) {
    unsigned u = __builtin_bit_cast(unsigned, f);
    unsigned r = u + 0x7FFFu + ((u >> 16) & 1u);   // RNE
    return (unsigned short)(r >> 16);
}

// one instr: packs bf16(lo) | bf16(hi)<<16, RNE (same result as f2bf pair)
__device__ __forceinline__ unsigned cvtpk(float lo, float hi) {
    unsigned r;
    asm("v_cvt_pk_bf16_f32 %0, %1, %2" : "=v"(r) : "v"(lo), "v"(hi));
    return r;
}

// ---------------- merged prep: route flags + weight pack ----------------
// Wp[chunk 0..17][tile 0..4][lane 0..63][8] bf16 ; chunk = tap*2 + h, k = 32h + quad*8 + j
// Ap2[tile 0..3][lane][8] bf16 for the 1x1 (k = (c>>2)*8 + (c&3), j>=4 zero)
__global__ void k_prep(const int* __restrict__ mi, const int* __restrict__ ii,
                       unsigned char* __restrict__ flags, int half,
                       const float* __restrict__ hw_, const float* __restrict__ l1w,
                       const float* __restrict__ l2w,
                       unsigned short* __restrict__ Wp, unsigned short* __restrict__ Ap2) {
    int i = blockIdx.x * 256 + threadIdx.x;
    if (i < half) { flags[mi[i]] = 1; flags[ii[i]] = 0; }
    if (i < 18 * 5 * 64) {
        int lane = i & 63, tile = (i >> 6) % 5, chunk = i / 320;
        int tap = chunk >> 1, h = chunk & 1, ky = tap / 3, kx = tap % 3;
        int m = lane & 15, quad = lane >> 4;
        for (int j = 0; j < 8; j++) {
            int cin = h * 32 + quad * 8 + j;
            float wv;
            if (tile < 4) { int co = tile * 16 + m; wv = hw_[((co * 64 + cin) * 3 + ky) * 3 + kx]; }
            else          { wv = l1w[((m * 64 + cin) * 3 + ky) * 3 + kx]; }
            Wp[(size_t)i * 8 + j] = f2bf(wv);
        }
    }
    if (i < 4 * 64) {
        int lane = i & 63, tile = i >> 6;
        int m = lane & 15, quad = lane >> 4;
        for (int j = 0; j < 8; j++) {
            unsigned short v = 0;
            if (j < 4) { int c = quad * 4 + j; v = f2bf(l2w[(tile * 16 + m) * 16 + c]); }
            Ap2[(size_t)i * 8 + j] = v;
        }
    }
}

// ---------------- main fused MFMA kernel (reads NCHW fp32 directly) ----------------
// WG = 512 thr = 8 waves on the 8x32 tile; wave w owns row w (2 col-half frags).
// __launch_bounds__(512, 4): 4 waves/SIMD = 16 waves/CU = 2 blocks/CU -> 128-reg budget.
// (512, 6) demanded 24 waves/CU -> 85-reg budget -> VGPR_Count 40 + ~700 MB scratch
// spill traffic (measured rounds 2-3: WRITE_SIZE 154 -> 855 MB, 3.7x slowdown).
// Register file, not LDS, is the occupancy binder for this kernel.
// 1D grid, XCD-bijective swizzle. Staging task = (row, aligned 4-col group, 8-cin group):
// 8x ALIGNED global_load_dwordx4, v_cvt_pk_bf16_f32 repack, ds_write_b128 swizzled.
__global__ __launch_bounds__(512, 4) void k_main(
    const float* __restrict__ x,
    const unsigned short* __restrict__ Wp,
    const unsigned short* __restrict__ Ap2,
    const unsigned char* __restrict__ flags,
    float* __restrict__ out)
{
    __shared__ __align__(16) unsigned short X[SR * SC * 64];  // 43520 B

    const int tid = threadIdx.x;

    // XCD-aware bijective swizzle (2304 % 8 == 0)
    const int lin = blockIdx.x;
    const int des = (lin & 7) * XCD_CHUNK + (lin >> 3);
    const int xt  = des % NXTILE;
    const int rst = des / NXTILE;
    const int yt  = rst % NYTILE;
    const int b   = rst / NYTILE;
    const int x0  = xt * TC;
    const int y0  = yt * TR;

    const int lane = tid & 63;

    // issue first weight-chunk loads early (independent of staging)
    const int4_t* wp4 = (const int4_t*)Wp;
    short8 a_cur[5], a_nxt[5];
#pragma unroll
    for (int t = 0; t < 5; t++)
        a_cur[t] = __builtin_bit_cast(short8, wp4[t * 64 + lane]);

    // ---- stage tile: global NCHW fp32 -> LDS bf16 fragment layout ----
    const float* xb = x + (size_t)b * CIN * HWc;
#pragma unroll 1
    for (int t = tid; t < NTASK; t += 512) {
        int g   = t % NG;                // aligned 4-col group: cols 4g-4 .. 4g-1 rel. to x0
        int q   = (t / NG) & 7;          // 8-cin group
        int row = t / (NG * 8);
        int gy  = y0 + row - 1;
        int gx0 = x0 - 4 + g * 4;        // multiple of 4 -> 16B-aligned address
        bool yok  = (unsigned)gy < (unsigned)HH;
        bool fast = yok && (gx0 >= 0) && (gx0 <= WW - 4);
        const float* xp = xb + (size_t)(q * 8) * HWc + gy * WW + gx0;
        float4_t v[8];
        if (fast) {
#pragma unroll
            for (int c = 0; c < 8; c++)
                v[c] = *(const float4_t*)(xp + (size_t)c * HWc);
        } else {
#pragma unroll
            for (int c = 0; c < 8; c++)
#pragma unroll
                for (int e = 0; e < 4; e++) {
                    bool ok = yok && ((unsigned)(gx0 + e) < (unsigned)WW);
                    v[c][e] = ok ? xp[(size_t)c * HWc + e] : 0.f;
                }
        }
#pragma unroll
        for (int e = 0; e < 4; e++) {
            int col = g * 4 + e - 3;     // LDS col = gx - (x0-1); each col covered exactly once
            if ((unsigned)col < (unsigned)SC) {
                int4_t pk;
#pragma unroll
                for (int jj = 0; jj < 4; jj++)
                    pk[jj] = (int)cvtpk(v[2 * jj][e], v[2 * jj + 1][e]);
                int blk = q ^ (col & 7);
                *(int4_t*)&X[(row * SC + col) * 64 + blk * 8] = pk;
            }
        }
    }
    __syncthreads();

    const int w    = tid >> 6;       // wave 0..7 owns pixel row w
    const int n16  = lane & 15;
    const int quad = lane >> 4;

    float4_t acc[5][2];
#pragma unroll
    for (int t = 0; t < 5; t++)
#pragma unroll
        for (int f = 0; f < 2; f++) acc[t][f] = (float4_t)0.0f;

#pragma unroll 1
    for (int chunk = 0; chunk < 18; chunk++) {
        if (chunk < 17) {
#pragma unroll
            for (int t = 0; t < 5; t++)
                a_nxt[t] = __builtin_bit_cast(short8, wp4[((chunk + 1) * 5 + t) * 64 + lane]);
        }
        const int tap = chunk >> 1, h = chunk & 1;
        const int ky = tap / 3, kx = tap % 3;
        short8 bf[2];
#pragma unroll
        for (int f = 0; f < 2; f++) {
            int xh  = f * 16 + n16 + kx;
            int blk = (h * 4 + quad) ^ (xh & 7);
            bf[f] = __builtin_bit_cast(short8,
                    *(const int4_t*)&X[((w + ky) * SC + xh) * 64 + blk * 8]);
        }
#pragma unroll
        for (int f = 0; f < 2; f++)
#pragma unroll
            for (int t = 0; t < 5; t++)
                acc[t][f] = __builtin_amdgcn_mfma_f32_16x16x32_bf16(a_cur[t], bf[f], acc[t][f], 0, 0, 0);
#pragma unroll
        for (int t = 0; t < 5; t++) a_cur[t] = a_nxt[t];
    }

    // ---- epilogue: 1x1 low path via MFMA, routed select, plain store ----
    short8 a2[4];
    const int4_t* ap4 = (const int4_t*)Ap2;
#pragma unroll
    for (int t = 0; t < 4; t++)
        a2[t] = __builtin_bit_cast(short8, ap4[t * 64 + lane]);

#pragma unroll
    for (int f = 0; f < 2; f++) {
        float4_t m4 = acc[4][f];
        int4_t bi;
        bi[0] = (int)cvtpk(m4[0], m4[1]);
        bi[1] = (int)cvtpk(m4[2], m4[3]);
        bi[2] = 0;
        bi[3] = 0;
        short8 bfrag = __builtin_bit_cast(short8, bi);

        int gy = y0 + w, gx = x0 + f * 16 + n16;
        bool hiF = flags[b * HWc + gy * WW + gx] != 0;
        float* ob = out + (size_t)b * COUT * HWc + gy * WW + gx;
#pragma unroll
        for (int t = 0; t < 4; t++) {
            float4_t low = __builtin_amdgcn_mfma_f32_16x16x32_bf16(a2[t], bfrag, (float4_t)0.0f, 0, 0, 0);
            float4_t hi = acc[t][f];
#pragma unroll
            for (int i = 0; i < 4; i++) {
                int co = t * 16 + quad * 4 + i;
                ob[(size_t)co * HWc] = hiF ? hi[i] : low[i];
            }
        }
    }
}

extern "C" void kernel_launch(void* const* d_in, const int* in_sizes, int n_in,
                              void* d_out, int out_size, void* d_ws, size_t ws_size,
                              hipStream_t stream) {
    const float* x   = (const float*)d_in[0];
    const float* hw_ = (const float*)d_in[1];
    const float* l1w = (const float*)d_in[2];
    const float* l2w = (const float*)d_in[3];
    const int*   mi  = (const int*)d_in[4];
    const int*   ii  = (const int*)d_in[5];
    float*       out = (float*)d_out;

    // ws carve
    unsigned char*  flags = (unsigned char*)d_ws;
    size_t off = (NPIX + 15) & ~(size_t)15;
    unsigned short* Wp    = (unsigned short*)((char*)d_ws + off); off += 18 * 5 * 64 * 8 * 2;
    unsigned short* Ap2   = (unsigned short*)((char*)d_ws + off);

    const int half = NPIX / 2;
    k_prep<<<(half + 255) / 256, 256, 0, stream>>>(mi, ii, flags, half, hw_, l1w, l2w, Wp, Ap2);
    k_main<<<NBLK, 512, 0, stream>>>(x, Wp, Ap2, flags, out);
}

// Round 6
// 315.249 us; speedup vs baseline: 2.0991x; 1.0515x over previous
//
#include <hip/hip_runtime.h>
#include <hip/hip_bf16.h>
#include <stdint.h>

typedef __attribute__((ext_vector_type(8))) short  short8;
typedef __attribute__((ext_vector_type(4))) float  float4_t;
typedef __attribute__((ext_vector_type(4))) int    int4_t;

constexpr int BB = 4, CIN = 64, COUT = 64, HH = 384, WW = 384;
constexpr int HWc  = HH * WW;        // 147456
constexpr int NPIX = BB * HWc;       // 589824
// main-kernel tiling
constexpr int TR = 8, TC = 32;           // pixel tile per WG
constexpr int SR = TR + 2, SC = TC + 2;  // staged rows/cols (10, 34)
constexpr int NG = 10;                   // 16B-aligned 4-col groups per row (cols x0-4 .. x0+35)
constexpr int NTASK = SR * NG * 8;       // staging tasks: row x group x 8-cin-group = 800
constexpr int NXTILE = WW / TC;          // 12
constexpr int NYTILE = HH / TR;          // 48
constexpr int NBLK  = NXTILE * NYTILE * BB;   // 2304
constexpr int XCD_CHUNK = NBLK / 8;           // 288 (2304 % 8 == 0 -> bijective)

__device__ __forceinline__ unsigned short f2bf(float f) {
    unsigned u = __builtin_bit_cast(unsigned, f);
    unsigned r = u + 0x7FFFu + ((u >> 16) & 1u);   // RNE
    return (unsigned short)(r >> 16);
}

// one instr: packs bf16(lo) | bf16(hi)<<16, RNE (same result as f2bf pair)
__device__ __forceinline__ unsigned cvtpk(float lo, float hi) {
    unsigned r;
    asm("v_cvt_pk_bf16_f32 %0, %1, %2" : "=v"(r) : "v"(lo), "v"(hi));
    return r;
}

// ---------------- merged prep: route flags + weight pack ----------------
// Wp[chunk 0..17][tile 0..4][lane 0..63][8] bf16 ; chunk = tap*2 + h, k = 32h + quad*8 + j
// Ap2[tile 0..3][lane][8] bf16 for the 1x1 (k = (c>>2)*8 + (c&3), j>=4 zero)
__global__ void k_prep(const int* __restrict__ mi, const int* __restrict__ ii,
                       unsigned char* __restrict__ flags, int half,
                       const float* __restrict__ hw_, const float* __restrict__ l1w,
                       const float* __restrict__ l2w,
                       unsigned short* __restrict__ Wp, unsigned short* __restrict__ Ap2) {
    int i = blockIdx.x * 256 + threadIdx.x;
    if (i < half) { flags[mi[i]] = 1; flags[ii[i]] = 0; }
    if (i < 18 * 5 * 64) {
        int lane = i & 63, tile = (i >> 6) % 5, chunk = i / 320;
        int tap = chunk >> 1, h = chunk & 1, ky = tap / 3, kx = tap % 3;
        int m = lane & 15, quad = lane >> 4;
        for (int j = 0; j < 8; j++) {
            int cin = h * 32 + quad * 8 + j;
            float wv;
            if (tile < 4) { int co = tile * 16 + m; wv = hw_[((co * 64 + cin) * 3 + ky) * 3 + kx]; }
            else          { wv = l1w[((m * 64 + cin) * 3 + ky) * 3 + kx]; }
            Wp[(size_t)i * 8 + j] = f2bf(wv);
        }
    }
    if (i < 4 * 64) {
        int lane = i & 63, tile = i >> 6;
        int m = lane & 15, quad = lane >> 4;
        for (int j = 0; j < 8; j++) {
            unsigned short v = 0;
            if (j < 4) { int c = quad * 4 + j; v = f2bf(l2w[(tile * 16 + m) * 16 + c]); }
            Ap2[(size_t)i * 8 + j] = v;
        }
    }
}

// staging task u in [0, NTASK): g = u%NG (aligned 4-col group), q = (u/NG)&7 (8-cin
// group), row = u/(NG*8). Loads 8x ALIGNED global_load_dwordx4.
__device__ __forceinline__ void issue_task(const float* __restrict__ xb, int x0, int y0,
                                           int u, float4_t* v) {
    int g = u % NG, q = (u / NG) & 7, row = u / (NG * 8);
    int gy  = y0 + row - 1;
    int gx0 = x0 - 4 + g * 4;            // multiple of 4 -> 16B-aligned address
    bool yok  = (unsigned)gy < (unsigned)HH;
    bool fast = yok && (gx0 >= 0) && (gx0 <= WW - 4);
    const float* xp = xb + (size_t)(q * 8) * HWc + gy * WW + gx0;
    if (fast) {
#pragma unroll
        for (int c = 0; c < 8; c++)
            v[c] = *(const float4_t*)(xp + (size_t)c * HWc);
    } else {
#pragma unroll
        for (int c = 0; c < 8; c++)
#pragma unroll
            for (int e = 0; e < 4; e++) {
                bool ok = yok && ((unsigned)(gx0 + e) < (unsigned)WW);
                v[c][e] = ok ? xp[(size_t)c * HWc + e] : 0.f;
            }
    }
}

// convert + swizzled LDS write for one task (same layout as verified round-1 kernel)
__device__ __forceinline__ void write_task(unsigned short* Xs, int u, const float4_t* v) {
    int g = u % NG, q = (u / NG) & 7, row = u / (NG * 8);
#pragma unroll
    for (int e = 0; e < 4; e++) {
        int col = g * 4 + e - 3;         // LDS col = gx - (x0-1); each col covered once
        if ((unsigned)col < (unsigned)SC) {
            int4_t pk;
#pragma unroll
            for (int jj = 0; jj < 4; jj++)
                pk[jj] = (int)cvtpk(v[2 * jj][e], v[2 * jj + 1][e]);
            int blk = q ^ (col & 7);
            *(int4_t*)&Xs[(row * SC + col) * 64 + blk * 8] = pk;
        }
    }
}

// ---------------- main fused MFMA kernel (reads NCHW fp32 directly) ----------------
// WG = 256 thr = 4 waves; pixel tile TR(8) x TC(32); wave w owns rows 2w,2w+1 (4 frags).
// Staging restructured for memory-level parallelism: the serial {8 loads -> wait ->
// convert -> write} x3.1 loop (8 loads in flight/wave) becomes issue-ALL-then-write-ALL
// (~25-32 loads in flight/wave). Sync structure identical to the verified round-1 kernel
// (single barrier, no concurrent LDS read/write windows).
// History: (512,6) -> 85-reg budget -> spills (WRITE 855 MB, 3.7x slow). NT stores ->
// 5.3x write amp. 16 waves/CU no better than 12. Half-pipelined staging -> NaN (reverted).
__global__ __launch_bounds__(256, 3) void k_main(
    const float* __restrict__ x,
    const unsigned short* __restrict__ Wp,
    const unsigned short* __restrict__ Ap2,
    const unsigned char* __restrict__ flags,
    float* __restrict__ out)
{
    __shared__ __align__(16) unsigned short X[SR * SC * 64];  // 43520 B -> 3 blocks/CU

    const int tid = threadIdx.x;

    // XCD-aware bijective swizzle (2304 % 8 == 0)
    const int lin = blockIdx.x;
    const int des = (lin & 7) * XCD_CHUNK + (lin >> 3);
    const int xt  = des % NXTILE;
    const int rst = des / NXTILE;
    const int yt  = rst % NYTILE;
    const int b   = rst / NYTILE;
    const int x0  = xt * TC;
    const int y0  = yt * TR;

    const int lane = tid & 63;
    const float* xb = x + (size_t)b * CIN * HWc;

    // ---- stage tile: issue all loads first (MLP), then convert+write, one barrier ----
    float4_t v0[8], v1[8], v2[8], v3[8];
    const bool has3 = tid < (NTASK - 768);         // 32 threads get a 4th task
    issue_task(xb, x0, y0, tid,       v0);
    issue_task(xb, x0, y0, tid + 256, v1);
    issue_task(xb, x0, y0, tid + 512, v2);
    if (has3) issue_task(xb, x0, y0, tid + 768, v3);

    write_task(X, tid,       v0);
    write_task(X, tid + 256, v1);
    write_task(X, tid + 512, v2);
    if (has3) write_task(X, tid + 768, v3);

    // first weight chunk preload (overlaps barrier wait; after staging to cap reg peak)
    const int4_t* wp4 = (const int4_t*)Wp;
    short8 a_cur[5], a_nxt[5];
#pragma unroll
    for (int t = 0; t < 5; t++)
        a_cur[t] = __builtin_bit_cast(short8, wp4[t * 64 + lane]);

    __syncthreads();

    const int w    = tid >> 6;
    const int n16  = lane & 15;
    const int quad = lane >> 4;

    float4_t acc[5][4];
#pragma unroll
    for (int t = 0; t < 5; t++)
#pragma unroll
        for (int f = 0; f < 4; f++) acc[t][f] = (float4_t)0.0f;

#pragma unroll 1
    for (int chunk = 0; chunk < 18; chunk++) {
        if (chunk < 17) {
#pragma unroll
            for (int t = 0; t < 5; t++)
                a_nxt[t] = __builtin_bit_cast(short8, wp4[((chunk + 1) * 5 + t) * 64 + lane]);
        }
        const int tap = chunk >> 1, h = chunk & 1;
        const int ky = tap / 3, kx = tap % 3;
        short8 bf[4];
#pragma unroll
        for (int f = 0; f < 4; f++) {
            int r  = 2 * w + (f >> 1);
            int ch = f & 1;
            int xh  = ch * 16 + n16 + kx;
            int blk = (h * 4 + quad) ^ (xh & 7);
            bf[f] = __builtin_bit_cast(short8,
                    *(const int4_t*)&X[((r + ky) * SC + xh) * 64 + blk * 8]);
        }
#pragma unroll
        for (int f = 0; f < 4; f++)
#pragma unroll
            for (int t = 0; t < 5; t++)
                acc[t][f] = __builtin_amdgcn_mfma_f32_16x16x32_bf16(a_cur[t], bf[f], acc[t][f], 0, 0, 0);
#pragma unroll
        for (int t = 0; t < 5; t++) a_cur[t] = a_nxt[t];
    }

    // ---- epilogue: 1x1 low path via MFMA, routed select, plain store ----
    short8 a2[4];
    const int4_t* ap4 = (const int4_t*)Ap2;
#pragma unroll
    for (int t = 0; t < 4; t++)
        a2[t] = __builtin_bit_cast(short8, ap4[t * 64 + lane]);

#pragma unroll
    for (int f = 0; f < 4; f++) {
        int r  = 2 * w + (f >> 1);
        int ch = f & 1;
        float4_t m4 = acc[4][f];
        int4_t bi;
        bi[0] = (int)cvtpk(m4[0], m4[1]);
        bi[1] = (int)cvtpk(m4[2], m4[3]);
        bi[2] = 0;
        bi[3] = 0;
        short8 bfrag = __builtin_bit_cast(short8, bi);

        int gy = y0 + r, gx = x0 + ch * 16 + n16;
        bool hiF = flags[b * HWc + gy * WW + gx] != 0;
        float* ob = out + (size_t)b * COUT * HWc + gy * WW + gx;
#pragma unroll
        for (int t = 0; t < 4; t++) {
            float4_t low = __builtin_amdgcn_mfma_f32_16x16x32_bf16(a2[t], bfrag, (float4_t)0.0f, 0, 0, 0);
            float4_t hi = acc[t][f];
#pragma unroll
            for (int i = 0; i < 4; i++) {
                int co = t * 16 + quad * 4 + i;
                ob[(size_t)co * HWc] = hiF ? hi[i] : low[i];
            }
        }
    }
}

extern "C" void kernel_launch(void* const* d_in, const int* in_sizes, int n_in,
                              void* d_out, int out_size, void* d_ws, size_t ws_size,
                              hipStream_t stream) {
    const float* x   = (const float*)d_in[0];
    const float* hw_ = (const float*)d_in[1];
    const float* l1w = (const float*)d_in[2];
    const float* l2w = (const float*)d_in[3];
    const int*   mi  = (const int*)d_in[4];
    const int*   ii  = (const int*)d_in[5];
    float*       out = (float*)d_out;

    // ws carve
    unsigned char*  flags = (unsigned char*)d_ws;
    size_t off = (NPIX + 15) & ~(size_t)15;
    unsigned short* Wp    = (unsigned short*)((char*)d_ws + off); off += 18 * 5 * 64 * 8 * 2;
    unsigned short* Ap2   = (unsigned short*)((char*)d_ws + off);

    const int half = NPIX / 2;
    k_prep<<<(half + 255) / 256, 256, 0, stream>>>(mi, ii, flags, half, hw_, l1w, l2w, Wp, Ap2);
    k_main<<<NBLK, 256, 0, stream>>>(x, Wp, Ap2, flags, out);
}